// Round 2
// baseline (2562.242 us; speedup 1.0000x reference)
//
#include <hip/hip_runtime.h>
#include <math.h>

#define N_TOK 16384
#define DDIM  384
#define KCODE 8192
#define EMA   0.99f
#define EPS_F 1e-5f

// argmin kernel tiling: 256 threads = 16(ty: token groups) x 16(tx: code groups)
// per-thread microtile: 8 tokens x 16 codes
#define BM 128       // tokens per block
#define BN 256       // codes per chunk
#define DC 16        // d-chunk
#define KSPLIT 4     // code-range splits (parallelism: 128 x 4 = 512 blocks)
#define ZSTRIDE 132  // 128 + 4 pad -> staging writes <=2-way, reads <=2-way
#define CSTRIDE 260  // 256 + 4 pad

// ------- ws layout (float units) -------
#define WS_COUNTS   16384
#define WS_EMBED    24576
#define WS_SUMSQ    3170304
#define WS_NACC     3170305
#define WS_CNORM    3170306
#define WS_PARTD    3178498
#define WS_PARTI    3244034

__global__ void cnorm_kernel(const float* __restrict__ cb, float* __restrict__ cnorm) {
    int wave = (blockIdx.x * blockDim.x + threadIdx.x) >> 6;
    int lane = threadIdx.x & 63;
    if (wave >= KCODE) return;
    const float* row = cb + wave * DDIM;
    float s = 0.f;
    #pragma unroll
    for (int r = 0; r < 6; r++) { float v = row[lane + 64 * r]; s += v * v; }
    #pragma unroll
    for (int off = 32; off > 0; off >>= 1) s += __shfl_down(s, off, 64);
    if (lane == 0) cnorm[wave] = s;
}

__launch_bounds__(256, 2)
__global__ void argmin_kernel(const float* __restrict__ z, const float* __restrict__ cb,
                              const float* __restrict__ cnorm,
                              float* __restrict__ part_d, int* __restrict__ part_i) {
    __shared__ float zs[DC * ZSTRIDE];   //  8448 B
    __shared__ float cs[DC * CSTRIDE];   // 16640 B

    const int tid = threadIdx.x;
    const int tx = tid & 15;          // code group
    const int ty = tid >> 4;          // token group
    const int m0 = blockIdx.x * BM;
    const int ks = blockIdx.y;
    const int k_begin = ks * (KCODE / KSPLIT);
    const int k_end   = k_begin + (KCODE / KSPLIT);

    // staging lane mapping (shared by z and c stages)
    const int smm = tid >> 2;         // 0..63: row within 64-row group
    const int scc = tid & 3;          // 0..3: which float4 chunk of DC=16 dims

    float best[8];
    int   besti[8];
    #pragma unroll
    for (int a = 0; a < 8; a++) { best[a] = 3.4e38f; besti[a] = 0; }

    for (int kc = k_begin; kc < k_end; kc += BN) {
        float acc[8][16];
        #pragma unroll
        for (int a = 0; a < 8; a++)
            #pragma unroll
            for (int b = 0; b < 16; b++) acc[a][b] = 0.f;

        for (int dc = 0; dc < DDIM; dc += DC) {
            // stage z tile transposed: zs[d][m]; banks = (16*(scc&1)+4e+smm)%32 -> <=2-way
            #pragma unroll
            for (int r = 0; r < 2; r++) {
                int m = smm + r * 64;
                const float4 v = *reinterpret_cast<const float4*>(
                    z + (size_t)(m0 + m) * DDIM + dc + scc * 4);
                zs[(scc * 4 + 0) * ZSTRIDE + m] = v.x;
                zs[(scc * 4 + 1) * ZSTRIDE + m] = v.y;
                zs[(scc * 4 + 2) * ZSTRIDE + m] = v.z;
                zs[(scc * 4 + 3) * ZSTRIDE + m] = v.w;
            }
            // stage code tile transposed: cs[d][n]
            #pragma unroll
            for (int r = 0; r < 4; r++) {
                int n = smm + r * 64;
                const float4 v = *reinterpret_cast<const float4*>(
                    cb + (size_t)(kc + n) * DDIM + dc + scc * 4);
                cs[(scc * 4 + 0) * CSTRIDE + n] = v.x;
                cs[(scc * 4 + 1) * CSTRIDE + n] = v.y;
                cs[(scc * 4 + 2) * CSTRIDE + n] = v.z;
                cs[(scc * 4 + 3) * CSTRIDE + n] = v.w;
            }
            __syncthreads();
            #pragma unroll
            for (int d = 0; d < DC; d++) {
                // tokens: m_local = jz*64 + ty*4 + e  (a = jz*4+e)
                float4 z0 = *reinterpret_cast<const float4*>(zs + d * ZSTRIDE + ty * 4);
                float4 z1 = *reinterpret_cast<const float4*>(zs + d * ZSTRIDE + 64 + ty * 4);
                // codes: n_local = j*64 + tx*4 + e   (b = j*4+e)
                float4 c0 = *reinterpret_cast<const float4*>(cs + d * CSTRIDE + tx * 4);
                float4 c1 = *reinterpret_cast<const float4*>(cs + d * CSTRIDE + 64 + tx * 4);
                float4 c2 = *reinterpret_cast<const float4*>(cs + d * CSTRIDE + 128 + tx * 4);
                float4 c3 = *reinterpret_cast<const float4*>(cs + d * CSTRIDE + 192 + tx * 4);
                float zv[8] = {z0.x, z0.y, z0.z, z0.w, z1.x, z1.y, z1.z, z1.w};
                float cv[16] = {c0.x, c0.y, c0.z, c0.w, c1.x, c1.y, c1.z, c1.w,
                                c2.x, c2.y, c2.z, c2.w, c3.x, c3.y, c3.z, c3.w};
                #pragma unroll
                for (int a = 0; a < 8; a++)
                    #pragma unroll
                    for (int b = 0; b < 16; b++)
                        acc[a][b] = fmaf(zv[a], cv[b], acc[a][b]);
            }
            __syncthreads();
        }
        // epilogue: dist = ||c||^2 - 2 z.c
        #pragma unroll
        for (int j = 0; j < 4; j++) {
            float4 cn = *reinterpret_cast<const float4*>(cnorm + kc + j * 64 + tx * 4);
            float cnv[4] = {cn.x, cn.y, cn.z, cn.w};
            #pragma unroll
            for (int e = 0; e < 4; e++) {
                int id = kc + j * 64 + tx * 4 + e;
                #pragma unroll
                for (int a = 0; a < 8; a++) {
                    float dist = cnv[e] - 2.f * acc[a][j * 4 + e];
                    if (dist < best[a]) { best[a] = dist; besti[a] = id; }
                }
            }
        }
    }

    // reduce over the 16 tx within each wave's 16-lane groups (same token set)
    #pragma unroll
    for (int a = 0; a < 8; a++) {
        float bd = best[a];
        int   bi = besti[a];
        #pragma unroll
        for (int off = 8; off > 0; off >>= 1) {
            float od = __shfl_xor(bd, off, 16);
            int   oi = __shfl_xor(bi, off, 16);
            if (od < bd || (od == bd && oi < bi)) { bd = od; bi = oi; }
        }
        if (tx == 0) {
            int m = m0 + (a >> 2) * 64 + ty * 4 + (a & 3);
            part_d[(size_t)m * KSPLIT + ks] = bd;
            part_i[(size_t)m * KSPLIT + ks] = bi;
        }
    }
}

__global__ void merge_kernel(const float* __restrict__ pd, const int* __restrict__ pi,
                             int* __restrict__ ws_idx, float* __restrict__ out_idx) {
    int t = blockIdx.x * blockDim.x + threadIdx.x;
    if (t >= N_TOK) return;
    float bd = pd[t * KSPLIT];
    int   bi = pi[t * KSPLIT];
    #pragma unroll
    for (int x = 1; x < KSPLIT; x++) {
        float dd = pd[t * KSPLIT + x];
        int   ii = pi[t * KSPLIT + x];
        if (dd < bd || (dd == bd && ii < bi)) { bd = dd; bi = ii; }
    }
    ws_idx[t] = bi;
    out_idx[t] = (float)bi;
}

// one wave per token: gather quantized, accumulate loss, scatter EMA stats
__global__ void gather_scatter_kernel(const float* __restrict__ z, const float* __restrict__ cb,
                                      const int* __restrict__ ws_idx,
                                      float* __restrict__ out_q, float* __restrict__ embed_ws,
                                      float* __restrict__ counts, float* __restrict__ sumsq) {
    int t = (blockIdx.x * blockDim.x + threadIdx.x) >> 6;
    int lane = threadIdx.x & 63;
    if (t >= N_TOK) return;
    int k = ws_idx[t];
    const float* zr = z + (size_t)t * DDIM;
    const float* cr = cb + (size_t)k * DDIM;
    float* qr = out_q + (size_t)t * DDIM;
    float* er = embed_ws + (size_t)k * DDIM;
    float s = 0.f;
    #pragma unroll
    for (int r = 0; r < 6; r++) {
        int d = lane + 64 * r;
        float zv = zr[d];
        float qv = cr[d];
        qr[d] = qv;
        float df = zv - qv;
        s += df * df;
        atomicAdd(er + d, zv);
    }
    #pragma unroll
    for (int off = 32; off > 0; off >>= 1) s += __shfl_down(s, off, 64);
    if (lane == 0) {
        atomicAdd(sumsq, s);
        atomicAdd(counts + k, 1.0f);
    }
}

__global__ void cluster_kernel(const float* __restrict__ ema_cs, const float* __restrict__ counts,
                               float* __restrict__ out_ncs, float* __restrict__ n_acc,
                               const float* __restrict__ sumsq, float* __restrict__ out_loss) {
    int i = blockIdx.x * blockDim.x + threadIdx.x;
    float v = 0.f;
    if (i < KCODE) {
        v = EMA * ema_cs[i] + (1.f - EMA) * counts[i];
        out_ncs[i] = v;
    }
    __shared__ float sm[4];
    int lane = threadIdx.x & 63, w = threadIdx.x >> 6;
    #pragma unroll
    for (int off = 32; off > 0; off >>= 1) v += __shfl_down(v, off, 64);
    if (lane == 0) sm[w] = v;
    __syncthreads();
    if (threadIdx.x == 0) {
        atomicAdd(n_acc, sm[0] + sm[1] + sm[2] + sm[3]);
        if (blockIdx.x == 0) {
            out_loss[0] = 1.25f * sumsq[0] / (float)(N_TOK * DDIM);
        }
    }
}

__global__ void codebook_kernel(const float* __restrict__ ema_es, const float* __restrict__ embed_ws,
                                const float* __restrict__ ncs, const float* __restrict__ n_acc,
                                float* __restrict__ out_es, float* __restrict__ out_cb) {
    int i = blockIdx.x * blockDim.x + threadIdx.x;
    if (i >= KCODE * DDIM) return;
    float es = EMA * ema_es[i] + (1.f - EMA) * embed_ws[i];
    out_es[i] = es;
    int k = i / DDIM;
    float n = n_acc[0];
    float smooth = (ncs[k] + EPS_F) / (n + (float)KCODE * EPS_F) * n;
    out_cb[i] = es / smooth;
}

extern "C" void kernel_launch(void* const* d_in, const int* in_sizes, int n_in,
                              void* d_out, int out_size, void* d_ws, size_t ws_size,
                              hipStream_t stream) {
    const float* z       = (const float*)d_in[0];
    const float* cb      = (const float*)d_in[1];
    const float* ema_cs  = (const float*)d_in[2];
    const float* ema_es  = (const float*)d_in[3];

    float* out      = (float*)d_out;
    float* out_q    = out;                       // 6291456
    float* out_idx  = out + 6291456;             // 16384
    float* out_loss = out + 6307840;             // 1
    float* out_ncs  = out + 6307841;             // 8192
    float* out_es   = out + 6316033;             // 3145728
    float* out_cb   = out + 9461761;             // 3145728

    float* ws      = (float*)d_ws;
    int*   ws_idx  = (int*)ws;
    float* counts  = ws + WS_COUNTS;
    float* embed   = ws + WS_EMBED;
    float* sumsq   = ws + WS_SUMSQ;
    float* n_acc   = ws + WS_NACC;
    float* cnorm   = ws + WS_CNORM;
    float* part_d  = ws + WS_PARTD;
    int*   part_i  = (int*)(ws + WS_PARTI);

    hipMemsetAsync(counts, 0, (size_t)(WS_CNORM - WS_COUNTS) * sizeof(float), stream);

    cnorm_kernel<<<KCODE * 64 / 256, 256, 0, stream>>>(cb, cnorm);
    dim3 grid_am(N_TOK / BM, KSPLIT, 1);
    argmin_kernel<<<grid_am, 256, 0, stream>>>(z, cb, cnorm, part_d, part_i);
    merge_kernel<<<N_TOK / 256, 256, 0, stream>>>(part_d, part_i, ws_idx, out_idx);
    gather_scatter_kernel<<<N_TOK * 64 / 256, 256, 0, stream>>>(z, cb, ws_idx, out_q, embed, counts, sumsq);
    cluster_kernel<<<(KCODE + 255) / 256, 256, 0, stream>>>(ema_cs, counts, out_ncs, n_acc, sumsq, out_loss);
    codebook_kernel<<<(KCODE * DDIM) / 256, 256, 0, stream>>>(ema_es, embed, out_ncs, n_acc, out_es, out_cb);
}